// Round 3
// baseline (217223.730 us; speedup 1.0000x reference)
//
#include <hip/hip_runtime.h>
#include <hip/hip_bf16.h>
#include <stdint.h>

#define B  64
#define TD 512
#define TE 1024
#define EE 512
#define UU 256

// ---------- numeric helpers ----------
__device__ __forceinline__ float fexp2(float x){ return __builtin_amdgcn_exp2f(x); }
__device__ __forceinline__ float frcp_(float x){ return __builtin_amdgcn_rcpf(x); }
__device__ __forceinline__ float tanh_fast(float x){
  float e = fexp2(x * 2.885390082f);
  return 1.f - 2.f * frcp_(e + 1.f);
}
__device__ __forceinline__ float sigmoid_fast(float x){
  return frcp_(1.f + fexp2(-1.442695041f * x));
}
__device__ __forceinline__ unsigned short f2bf(float f){
  unsigned int u = __float_as_uint(f);
  u = (u + 0x7fffu + ((u >> 16) & 1u)) >> 16;   // RNE
  return (unsigned short)u;
}
__device__ __forceinline__ float bflo(unsigned int w){ return __uint_as_float(w << 16); }
__device__ __forceinline__ float bfhi(unsigned int w){ return __uint_as_float(w & 0xffff0000u); }

// Cross-XCD comm WITHOUT cache flushes: relaxed system-scope ops lower to
// global_load/store/atomic with sc0 sc1 (bypass L1/L2, coherent at L3) and
// never emit buffer_inv/buffer_wbl2 -> L2 stays hot for enc/speech/KR.
__device__ __forceinline__ void gstore(float* p, float v){
  __hip_atomic_store(p, v, __ATOMIC_RELAXED, __HIP_MEMORY_SCOPE_SYSTEM);
}
__device__ __forceinline__ float gload(const float* p){
  return __hip_atomic_load(p, __ATOMIC_RELAXED, __HIP_MEMORY_SCOPE_SYSTEM);
}
__device__ __forceinline__ void drain_stores(){
  __atomic_signal_fence(__ATOMIC_SEQ_CST);
  __builtin_amdgcn_s_waitcnt(0);
  __atomic_signal_fence(__ATOMIC_SEQ_CST);
}

// ---------- pack kernels ----------
__global__ void pack_bf16v(const float* __restrict__ in, unsigned short* __restrict__ out, int n4){
  int i = blockIdx.x * blockDim.x + threadIdx.x;
  int stride = gridDim.x * blockDim.x;
  for (; i < n4; i += stride){
    float4 v = ((const float4*)in)[i];
    ushort4 o;
    o.x = f2bf(v.x); o.y = f2bf(v.y); o.z = f2bf(v.z); o.w = f2bf(v.w);
    ((ushort4*)out)[i] = o;
  }
}

// KR[k][j]: rows 0..767 = K, rows 768..1023 = R
__global__ void pack_KR(const float* __restrict__ K, const float* __restrict__ R,
                        unsigned short* __restrict__ KR){
  int idx = blockIdx.x * 256 + threadIdx.x;
  int k = idx >> 10;
  float v = (k < 768) ? K[idx] : R[idx - 768*1024];
  KR[idx] = f2bf(v);
}

// Wa2[k2][u] = uint(bf16(Wa[2k2][u]), bf16(Wa[2k2+1][u]))
__global__ void pack_Wa2(const float* __restrict__ W, unsigned int* __restrict__ out){
  int idx = blockIdx.x * 256 + threadIdx.x;    // 128 blocks
  int k2 = idx >> 8, u = idx & 255;
  unsigned int lo = f2bf(W[(size_t)(2*k2)*UU + u]);
  unsigned int hi = f2bf(W[(size_t)(2*k2+1)*UU + u]);
  out[idx] = lo | (hi << 16);
}

// ---------- secrets = trans @ emb_W + emb_b : [32768,64]@[64,256] ----------
__global__ __launch_bounds__(256) void emb_gemm(const float* __restrict__ trans,
    const float* __restrict__ W, const float* __restrict__ bias, float* __restrict__ out){
  __shared__ __align__(16) float aT[64*20];
  const int row0 = blockIdx.x * 16;
  const int tid = threadIdx.x;
  {
    int r = tid >> 6, k = tid & 63;
    for (int rr = r; rr < 16; rr += 4)
      aT[k*20 + rr] = trans[(size_t)(row0 + rr)*64 + k];
  }
  __syncthreads();
  const int j = tid;
  float bj = bias[j];
  float acc[16];
  #pragma unroll
  for (int r = 0; r < 16; ++r) acc[r] = bj;
  for (int k = 0; k < 64; ++k){
    float w = W[(size_t)k*UU + j];
    const float4* a4 = (const float4*)(aT + k*20);
    float4 q0 = a4[0], q1 = a4[1], q2 = a4[2], q3 = a4[3];
    acc[0]+=q0.x*w;  acc[1]+=q0.y*w;  acc[2]+=q0.z*w;  acc[3]+=q0.w*w;
    acc[4]+=q1.x*w;  acc[5]+=q1.y*w;  acc[6]+=q1.z*w;  acc[7]+=q1.w*w;
    acc[8]+=q2.x*w;  acc[9]+=q2.y*w;  acc[10]+=q2.z*w; acc[11]+=q2.w*w;
    acc[12]+=q3.x*w; acc[13]+=q3.y*w; acc[14]+=q3.z*w; acc[15]+=q3.w*w;
  }
  #pragma unroll
  for (int r = 0; r < 16; ++r)
    out[(size_t)(row0 + r)*UU + j] = acc[r];
}

// ---------- enc = speech @ Ua + Ua_b, stored bf16 [B][TE][U] ----------
__global__ __launch_bounds__(256) void enc_gemm(const float* __restrict__ speech,
    const float* __restrict__ Ua, const float* __restrict__ Uab,
    unsigned short* __restrict__ enc){
  __shared__ __align__(16) float aT[512*20];
  const int wg = blockIdx.x;
  const int b = wg >> 6, tb = (wg & 63) * 16;
  const int tid = threadIdx.x;
  const float* sp = speech + ((size_t)b*TE + tb)*EE;
  for (int it = 0; it < 32; ++it){
    int idx = tid + 256*it;
    int te = idx >> 9, e = idx & 511;
    aT[e*20 + te] = sp[(size_t)te*EE + e];
  }
  __syncthreads();
  const int j = tid;
  float bj = Uab[j];
  float acc[16];
  #pragma unroll
  for (int r = 0; r < 16; ++r) acc[r] = bj;
  const float* up = Ua + j;
  for (int e = 0; e < 512; ++e){
    float w = up[(size_t)e*UU];
    const float4* a4 = (const float4*)(aT + e*20);
    float4 q0 = a4[0], q1 = a4[1], q2 = a4[2], q3 = a4[3];
    acc[0]+=q0.x*w;  acc[1]+=q0.y*w;  acc[2]+=q0.z*w;  acc[3]+=q0.w*w;
    acc[4]+=q1.x*w;  acc[5]+=q1.y*w;  acc[6]+=q1.z*w;  acc[7]+=q1.w*w;
    acc[8]+=q2.x*w;  acc[9]+=q2.y*w;  acc[10]+=q2.z*w; acc[11]+=q2.w*w;
    acc[12]+=q3.x*w; acc[13]+=q3.y*w; acc[14]+=q3.z*w; acc[15]+=q3.w*w;
  }
  unsigned short* op = enc + ((size_t)b*TE + tb)*UU + j;
  #pragma unroll
  for (int r = 0; r < 16; ++r) op[(size_t)r*UU] = f2bf(acc[r]);
}

// ---------- persistent attention-LSTM scan ----------
// grid 256 = 64 batches x 4 WGs; 1024 threads, 128 VGPR (launch_bounds 4 w/EU).
// Streaming loops: chunked register preloads (8 wide loads in flight).
// Gate x/h half + x-prefetch execute in the barrier arrive->spin shadow.
__global__ __launch_bounds__(1024, 4) void scan_kernel(
    const float* __restrict__ x_seq, float* __restrict__ y_out,
    const unsigned short* __restrict__ enc, const unsigned short* __restrict__ speech,
    const unsigned short* __restrict__ KR, const unsigned int* __restrict__ Wab2,
    const float* __restrict__ Wa_b, const float* __restrict__ va,
    const float* __restrict__ gate_b,
    float* __restrict__ pctx_g, float* __restrict__ l_g, float* __restrict__ h_g,
    unsigned int* __restrict__ ctr){
  __shared__ float2 sva[256];        // (s[u], va[u])
  __shared__ float cat[1024];        // [0,256)=x_t  [256,768)=ctx  [768,1024)=h_{t-1}
  __shared__ float c_lds[64];
  __shared__ float lds_logit[256];
  __shared__ float p_lds[256];
  __shared__ float lds_pctx[512];
  __shared__ float lds_z[256];
  __shared__ float s_acc[256];
  __shared__ float red[32];
  __shared__ float nmi[2];

  const int tid = threadIdx.x;
  const int wg = blockIdx.x;
  const int b = wg >> 2, q = wg & 3;
  const int lane = tid & 63, wave = tid >> 6;
  unsigned int bar = 0;
  unsigned int* cptr = &ctr[b*16];

  if (tid < 256){
    sva[tid] = make_float2(Wa_b[tid], va[tid]);
    cat[768 + tid] = 0.f;
    lds_logit[tid] = 0.f;
    lds_z[tid] = 0.f;
    cat[tid] = x_seq[((size_t)b*TD)*UU + tid];    // x_0
  }
  if (tid < 512) lds_pctx[tid] = 0.f;
  if (tid < 64) c_lds[tid] = 0.f;
  __syncthreads();

  for (int t = 0; t < TD; ++t){
    // ---- P1: attention logits over this WG's te chunk (8 uint4 preloaded) ----
    {
      const int g = wave & 3, r = wave >> 2;
      const int te = q*256 + g*64 + lane;
      const unsigned short* ep = enc + ((size_t)b*TE + te)*UU + r*64;
      uint4 v[8];
      #pragma unroll
      for (int c = 0; c < 8; ++c) v[c] = *(const uint4*)(ep + c*8);
      float acc = 0.f;
      #pragma unroll
      for (int c = 0; c < 8; ++c){
        const int ub = r*64 + c*8;
        unsigned int wv[4] = {v[c].x, v[c].y, v[c].z, v[c].w};
        #pragma unroll
        for (int i = 0; i < 4; ++i){
          float2 s0 = sva[ub + 2*i];
          float2 s1 = sva[ub + 2*i + 1];
          acc += s0.y * tanh_fast(s0.x + bflo(wv[i]));
          acc += s1.y * tanh_fast(s1.x + bfhi(wv[i]));
        }
      }
      atomicAdd(&lds_logit[g*64 + lane], acc);
    }
    __syncthreads();

    // ---- P2: p = exp(logit), wave partial sums ----
    if (tid < 256){
      float p = fexp2(lds_logit[tid] * 1.442695041f);
      p_lds[tid] = p;
      float s = p;
      #pragma unroll
      for (int o = 32; o > 0; o >>= 1) s += __shfl_xor(s, o);
      if (lane == 0) red[wave] = s;
    }
    __syncthreads();

    // ---- P3: partial ctx (uint2 chunks, 8 in flight) ----
    {
      const int epi = tid & 127, qq = tid >> 7;          // 4 e-cols, 32 te each
      const unsigned short* sp = speech + ((size_t)b*TE + q*256 + qq*32)*EE + epi*4;
      float a0 = 0.f, a1 = 0.f, a2 = 0.f, a3 = 0.f;
      #pragma unroll
      for (int c = 0; c < 4; ++c){
        uint2 w[8];
        #pragma unroll
        for (int j = 0; j < 8; ++j)
          w[j] = *(const uint2*)(sp + (size_t)(c*8 + j)*EE);
        #pragma unroll
        for (int j = 0; j < 8; ++j){
          float p = p_lds[qq*32 + c*8 + j];
          a0 += p * bflo(w[j].x); a1 += p * bfhi(w[j].x);
          a2 += p * bflo(w[j].y); a3 += p * bfhi(w[j].y);
        }
      }
      atomicAdd(&lds_pctx[epi*4 + 0], a0);
      atomicAdd(&lds_pctx[epi*4 + 1], a1);
      atomicAdd(&lds_pctx[epi*4 + 2], a2);
      atomicAdd(&lds_pctx[epi*4 + 3], a3);
    }
    __syncthreads();

    // ---- P4: export partials; re-zero next-step LDS in spare lanes ----
    if (tid < 512)      gstore(&pctx_g[((size_t)(b*4 + q))*512 + tid], lds_pctx[tid]);
    else if (tid < 768) s_acc[tid - 512] = 0.f;
    else                lds_logit[tid - 768] = 0.f;
    if (tid == 0) gstore(&l_g[b*4 + q], red[0] + red[1] + red[2] + red[3]);
    drain_stores();
    __syncthreads();
    bar += 4;
    if (tid == 0)
      __hip_atomic_fetch_add(cptr, 1u, __ATOMIC_RELAXED, __HIP_MEMORY_SCOPE_SYSTEM);

    // ---- P5 (barrier-A shadow): gate GEMV x-rows + h-rows ----
    {
      const int cp = tid & 63, kq = tid >> 6;            // 4 cols, 32 rows each
      const int c0 = cp*4;
      const int j0 = (c0 >> 6)*256 + q*64 + (c0 & 63);
      const int r0 = (kq < 8) ? kq*32 : 768 + (kq - 8)*32;
      const unsigned short* kp = KR + (size_t)r0*1024 + j0;
      float z0 = 0.f, z1 = 0.f, z2 = 0.f, z3 = 0.f;
      #pragma unroll
      for (int c = 0; c < 4; ++c){
        uint2 w[8];
        #pragma unroll
        for (int j = 0; j < 8; ++j)
          w[j] = *(const uint2*)(kp + (size_t)(c*8 + j)*1024);
        #pragma unroll
        for (int j = 0; j < 8; ++j){
          float ck = cat[r0 + c*8 + j];
          z0 += ck * bflo(w[j].x); z1 += ck * bfhi(w[j].x);
          z2 += ck * bflo(w[j].y); z3 += ck * bfhi(w[j].y);
        }
      }
      atomicAdd(&lds_z[c0 + 0], z0);
      atomicAdd(&lds_z[c0 + 1], z1);
      atomicAdd(&lds_z[c0 + 2], z2);
      atomicAdd(&lds_z[c0 + 3], z3);
    }
    if (tid == 0){
      while (__hip_atomic_load(cptr, __ATOMIC_RELAXED, __HIP_MEMORY_SCOPE_SYSTEM) < bar)
        __builtin_amdgcn_s_sleep(1);
    }
    __syncthreads();

    // ---- P7: merge ctx (system loads hoisted) ----
    if (tid < 512){
      float l0 = gload(&l_g[b*4+0]), l1 = gload(&l_g[b*4+1]);
      float l2 = gload(&l_g[b*4+2]), l3 = gload(&l_g[b*4+3]);
      float p0 = gload(&pctx_g[((size_t)(b*4+0))*512 + tid]);
      float p1 = gload(&pctx_g[((size_t)(b*4+1))*512 + tid]);
      float p2 = gload(&pctx_g[((size_t)(b*4+2))*512 + tid]);
      float p3 = gload(&pctx_g[((size_t)(b*4+3))*512 + tid]);
      cat[256 + tid] = (p0 + p1 + p2 + p3) * frcp_(l0 + l1 + l2 + l3);
    }
    __syncthreads();

    // ---- P8: gate GEMV ctx-rows ----
    {
      const int cp = tid & 63, kq = tid >> 6;
      const int c0 = cp*4;
      const int j0 = (c0 >> 6)*256 + q*64 + (c0 & 63);
      const int r0 = 256 + kq*32;
      const unsigned short* kp = KR + (size_t)r0*1024 + j0;
      float z0 = 0.f, z1 = 0.f, z2 = 0.f, z3 = 0.f;
      #pragma unroll
      for (int c = 0; c < 4; ++c){
        uint2 w[8];
        #pragma unroll
        for (int j = 0; j < 8; ++j)
          w[j] = *(const uint2*)(kp + (size_t)(c*8 + j)*1024);
        #pragma unroll
        for (int j = 0; j < 8; ++j){
          float ck = cat[r0 + c*8 + j];
          z0 += ck * bflo(w[j].x); z1 += ck * bfhi(w[j].x);
          z2 += ck * bflo(w[j].y); z3 += ck * bfhi(w[j].y);
        }
      }
      atomicAdd(&lds_z[c0 + 0], z0);
      atomicAdd(&lds_z[c0 + 1], z1);
      atomicAdd(&lds_z[c0 + 2], z2);
      atomicAdd(&lds_z[c0 + 3], z3);
    }
    __syncthreads();

    // ---- P9: LSTM pointwise (keras i,f,g,o), export h slice ----
    if (tid < 64){
      const int jj = q*64 + tid;
      float zi = lds_z[tid]       + gate_b[jj];
      float zf = lds_z[64 + tid]  + gate_b[256 + jj];
      float zg = lds_z[128 + tid] + gate_b[512 + jj];
      float zo = lds_z[192 + tid] + gate_b[768 + jj];
      float cn = sigmoid_fast(zf) * c_lds[tid] + sigmoid_fast(zi) * tanh_fast(zg);
      c_lds[tid] = cn;
      gstore(&h_g[(size_t)b*UU + jj], sigmoid_fast(zo) * tanh_fast(cn));
    }
    drain_stores();
    __syncthreads();
    bar += 4;
    if (tid == 0)
      __hip_atomic_fetch_add(cptr, 1u, __ATOMIC_RELAXED, __HIP_MEMORY_SCOPE_SYSTEM);

    // ---- P9.5 (barrier-B shadow): prefetch x_{t+1}, re-zero LDS ----
    {
      const int tn = (t + 1 < TD) ? t + 1 : t;
      if (tid < 256)      cat[tid] = x_seq[((size_t)b*TD + tn)*UU + tid];
      else if (tid < 768) lds_pctx[tid - 256] = 0.f;
      else                lds_z[tid - 768] = 0.f;
    }
    if (tid == 0){
      while (__hip_atomic_load(cptr, __ATOMIC_RELAXED, __HIP_MEMORY_SCOPE_SYSTEM) < bar)
        __builtin_amdgcn_s_sleep(1);
    }
    __syncthreads();

    // ---- P11: reload full h_t ----
    if (tid < 256) cat[768 + tid] = gload(&h_g[(size_t)b*UU + tid]);
    __syncthreads();

    // ---- P12a: y_t = whatever_norm(h_t), once per batch (WG-uniform branch) ----
    if (q == 0){
      if (tid < 256){
        float hv = cat[768 + tid];
        float s1 = hv, s2 = hv*hv;
        #pragma unroll
        for (int o = 32; o > 0; o >>= 1){ s1 += __shfl_xor(s1, o); s2 += __shfl_xor(s2, o); }
        if (lane == 0){ red[wave*2] = s1; red[wave*2 + 1] = s2; }
      }
      __syncthreads();
      if (tid == 0){
        float m  = (red[0] + red[2] + red[4] + red[6]) * (1.f/256.f);
        float ms = (red[1] + red[3] + red[5] + red[7]) * (1.f/256.f);
        nmi[0] = m;
        nmi[1] = rsqrtf(ms - m*m + 1e-4f);
      }
      __syncthreads();
      if (tid < 256)
        y_out[((size_t)b*TD + t)*UU + tid] = (cat[768 + tid] - nmi[0]) * nmi[1];
    }

    // ---- P12b: s_{t+1} = h_t @ Wa + Wa_b (redundant per WG, chunked) ----
    {
      const int u = tid & 255, kq2 = tid >> 8;
      const unsigned int* wp = Wab2 + (size_t)(kq2*32)*UU + u;
      float a = 0.f;
      #pragma unroll
      for (int c = 0; c < 4; ++c){
        unsigned int w[8];
        #pragma unroll
        for (int j = 0; j < 8; ++j) w[j] = wp[(size_t)(c*8 + j)*UU];
        #pragma unroll
        for (int j = 0; j < 8; ++j){
          const int kk = kq2*32 + c*8 + j;
          a += cat[768 + 2*kk]     * bflo(w[j]);
          a += cat[768 + 2*kk + 1] * bfhi(w[j]);
        }
      }
      atomicAdd(&s_acc[u], a);
    }
    __syncthreads();
    if (tid < 256) sva[tid].x = Wa_b[tid] + s_acc[tid];
    __syncthreads();
  }
}

// ---------- head: norm(norm(y2@m1+b)@m2+b)@dW+db -> softmax ----------
__global__ __launch_bounds__(256) void head_kernel(const float* __restrict__ y2,
    const float* __restrict__ m1W, const float* __restrict__ m1b,
    const float* __restrict__ m2W, const float* __restrict__ m2b,
    const float* __restrict__ dW, const float* __restrict__ db,
    float* __restrict__ out){
  __shared__ __align__(16) float aT[256*20];
  __shared__ float t_lds[16*256];
  __shared__ float zl[16*64];
  __shared__ float mi[32];
  const int row0 = blockIdx.x * 16;
  const int tid = threadIdx.x;
  for (int it = 0; it < 16; ++it){
    int idx = tid + 256*it;
    int r = idx >> 8, k = idx & 255;
    aT[k*20 + r] = y2[(size_t)(row0 + r)*UU + k];
  }
  __syncthreads();

  #pragma unroll 1
  for (int pass = 0; pass < 2; ++pass){
    const float* Wp = pass ? m2W : m1W;
    const float* bp = pass ? m2b : m1b;
    const int j = tid;
    float bj = bp[j];
    float acc[16];
    #pragma unroll
    for (int r = 0; r < 16; ++r) acc[r] = bj;
    for (int k = 0; k < 256; ++k){
      float w = Wp[(size_t)k*UU + j];
      const float4* a4 = (const float4*)(aT + k*20);
      float4 q0 = a4[0], q1 = a4[1], q2 = a4[2], q3 = a4[3];
      acc[0]+=q0.x*w;  acc[1]+=q0.y*w;  acc[2]+=q0.z*w;  acc[3]+=q0.w*w;
      acc[4]+=q1.x*w;  acc[5]+=q1.y*w;  acc[6]+=q1.z*w;  acc[7]+=q1.w*w;
      acc[8]+=q2.x*w;  acc[9]+=q2.y*w;  acc[10]+=q2.z*w; acc[11]+=q2.w*w;
      acc[12]+=q3.x*w; acc[13]+=q3.y*w; acc[14]+=q3.z*w; acc[15]+=q3.w*w;
    }
    #pragma unroll
    for (int r = 0; r < 16; ++r) t_lds[r*256 + j] = acc[r];
    __syncthreads();
    {
      int r = tid >> 4, sg = tid & 15;
      float s1 = 0.f, s2 = 0.f;
      for (int c = 0; c < 16; ++c){
        float v = t_lds[r*256 + sg*16 + c];
        s1 += v; s2 += v*v;
      }
      for (int o = 1; o < 16; o <<= 1){ s1 += __shfl_xor(s1, o); s2 += __shfl_xor(s2, o); }
      if (sg == 0){
        float m = s1 * (1.f/256.f);
        float vv = s2 * (1.f/256.f) - m*m;
        mi[r*2] = m; mi[r*2+1] = rsqrtf(vv + 1e-4f);
      }
    }
    __syncthreads();
    {
      const int j2 = tid;
      #pragma unroll
      for (int r = 0; r < 16; ++r)
        aT[j2*20 + r] = (t_lds[r*256 + j2] - mi[r*2]) * mi[r*2+1];
    }
    __syncthreads();
  }

  for (int i = tid; i < 1024; i += 256) zl[i] = 0.f;
  __syncthreads();
  {
    const int j = tid & 63, kq = tid >> 6;
    float acc[16];
    #pragma unroll
    for (int r = 0; r < 16; ++r) acc[r] = 0.f;
    for (int k = 0; k < 64; ++k){
      float w = dW[(size_t)(kq*64 + k)*64 + j];
      const float4* a4 = (const float4*)(aT + (kq*64 + k)*20);
      float4 q0 = a4[0], q1 = a4[1], q2 = a4[2], q3 = a4[3];
      acc[0]+=q0.x*w;  acc[1]+=q0.y*w;  acc[2]+=q0.z*w;  acc[3]+=q0.w*w;
      acc[4]+=q1.x*w;  acc[5]+=q1.y*w;  acc[6]+=q1.z*w;  acc[7]+=q1.w*w;
      acc[8]+=q2.x*w;  acc[9]+=q2.y*w;  acc[10]+=q2.z*w; acc[11]+=q2.w*w;
      acc[12]+=q3.x*w; acc[13]+=q3.y*w; acc[14]+=q3.z*w; acc[15]+=q3.w*w;
    }
    #pragma unroll
    for (int r = 0; r < 16; ++r) atomicAdd(&zl[r*64 + j], acc[r]);
  }
  __syncthreads();
  if (tid < 16){
    const int r = tid;
    float mx = -1e30f;
    for (int j = 0; j < 64; ++j){ float v = zl[r*64 + j] + db[j]; zl[r*64 + j] = v; mx = fmaxf(mx, v); }
    float s = 0.f;
    for (int j = 0; j < 64; ++j){ float e = fexp2((zl[r*64 + j] - mx) * 1.442695041f); zl[r*64 + j] = e; s += e; }
    mi[r] = frcp_(s);
  }
  __syncthreads();
  for (int it = 0; it < 4; ++it){
    int idx = tid + 256*it;
    int r = idx >> 6, j = idx & 63;
    out[(size_t)(row0 + r)*64 + j] = zl[r*64 + j] * mi[r];
  }
}

// ---------- workspace layout (bytes) ----------
#define OFF_SPEECH 0u
#define OFF_ENC    67108864u
#define OFF_KR     100663296u
#define OFF_WA     102760448u
#define OFF_X1     102891520u
#define OFF_Y1     136445952u
#define OFF_PCTX   170000384u
#define OFF_L      170524672u
#define OFF_H      170528768u
#define OFF_CTR    170594304u

extern "C" void kernel_launch(void* const* d_in, const int* in_sizes, int n_in,
                              void* d_out, int out_size, void* d_ws, size_t ws_size,
                              hipStream_t stream){
  const float* trans  = (const float*)d_in[0];
  const float* speech = (const float*)d_in[1];
  const float* emb_W  = (const float*)d_in[2];
  const float* emb_b  = (const float*)d_in[3];
  const float* Ua_W[2]  = {(const float*)d_in[4],  (const float*)d_in[13]};
  const float* Ua_b[2]  = {(const float*)d_in[5],  (const float*)d_in[14]};
  const float* Wa_W[2]  = {(const float*)d_in[6],  (const float*)d_in[15]};
  const float* Wa_bv[2] = {(const float*)d_in[7],  (const float*)d_in[16]};
  const float* va_W[2]  = {(const float*)d_in[8],  (const float*)d_in[17]};
  // d_in[9]/d_in[18] = va_b: constant logit shift, softmax-invariant, dropped exactly.
  const float* Kw[2]    = {(const float*)d_in[10], (const float*)d_in[19]};
  const float* Rw[2]    = {(const float*)d_in[11], (const float*)d_in[20]};
  const float* bw[2]    = {(const float*)d_in[12], (const float*)d_in[21]};
  const float* m1W = (const float*)d_in[22];
  const float* m1b = (const float*)d_in[23];
  const float* m2W = (const float*)d_in[24];
  const float* m2b = (const float*)d_in[25];
  const float* dW  = (const float*)d_in[26];
  const float* db  = (const float*)d_in[27];

  char* ws = (char*)d_ws;
  unsigned short* speech_bf = (unsigned short*)(ws + OFF_SPEECH);
  unsigned short* enc  = (unsigned short*)(ws + OFF_ENC);
  unsigned short* KR   = (unsigned short*)(ws + OFF_KR);
  unsigned int*   Wab2 = (unsigned int*)(ws + OFF_WA);
  float* x1   = (float*)(ws + OFF_X1);
  float* y1   = (float*)(ws + OFF_Y1);
  float* pctx = (float*)(ws + OFF_PCTX);
  float* lg   = (float*)(ws + OFF_L);
  float* hg   = (float*)(ws + OFF_H);
  unsigned int* ctr = (unsigned int*)(ws + OFF_CTR);
  float* y2 = x1;   // x1 dead after scan1 consumes it

  hipMemsetAsync(ctr, 0, 4096, stream);
  pack_bf16v<<<4096, 256, 0, stream>>>(speech, speech_bf, B*TE*EE/4);
  emb_gemm<<<2048, 256, 0, stream>>>(trans, emb_W, emb_b, x1);

  for (int L = 0; L < 2; ++L){
    enc_gemm<<<4096, 256, 0, stream>>>(speech, Ua_W[L], Ua_b[L], enc);
    pack_KR<<<4096, 256, 0, stream>>>(Kw[L], Rw[L], KR);
    pack_Wa2<<<128, 256, 0, stream>>>(Wa_W[L], Wab2);
    if (L == 1) hipMemsetAsync(ctr, 0, 4096, stream);
    scan_kernel<<<256, 1024, 0, stream>>>(L == 0 ? x1 : y1, L == 0 ? y1 : y2,
        enc, speech_bf, KR, Wab2, Wa_bv[L], va_W[L], bw[L], pctx, lg, hg, ctr);
  }

  head_kernel<<<2048, 256, 0, stream>>>(y2, m1W, m1b, m2W, m2b, dW, db, (float*)d_out);
  (void)in_sizes; (void)n_in; (void)out_size; (void)ws_size;
}

// Round 5
// 46899.106 us; speedup vs baseline: 4.6317x; 4.6317x over previous
//
#include <hip/hip_runtime.h>
#include <hip/hip_bf16.h>
#include <stdint.h>

#define B  64
#define TD 512
#define TE 1024
#define EE 512
#define UU 256

// ---------- numeric helpers ----------
__device__ __forceinline__ float fexp2(float x){ return __builtin_amdgcn_exp2f(x); }
__device__ __forceinline__ float frcp_(float x){ return __builtin_amdgcn_rcpf(x); }
__device__ __forceinline__ float tanh_fast(float x){
  float e = fexp2(x * 2.885390082f);
  return 1.f - 2.f * frcp_(e + 1.f);
}
__device__ __forceinline__ float sigmoid_fast(float x){
  return frcp_(1.f + fexp2(-1.442695041f * x));
}
__device__ __forceinline__ unsigned short f2bf(float f){
  unsigned int u = __float_as_uint(f);
  u = (u + 0x7fffu + ((u >> 16) & 1u)) >> 16;   // RNE
  return (unsigned short)u;
}
__device__ __forceinline__ float bflo(unsigned int w){ return __uint_as_float(w << 16); }
__device__ __forceinline__ float bfhi(unsigned int w){ return __uint_as_float(w & 0xffff0000u); }

// Cross-XCD comm WITHOUT cache flushes: relaxed system-scope ops lower to
// global_load/store/atomic with sc0 sc1 (bypass L1/L2, coherent at L3) and
// never emit buffer_inv/buffer_wbl2 -> L2 stays hot for speech/KR.
__device__ __forceinline__ void gstore(float* p, float v){
  __hip_atomic_store(p, v, __ATOMIC_RELAXED, __HIP_MEMORY_SCOPE_SYSTEM);
}
__device__ __forceinline__ float gload(const float* p){
  return __hip_atomic_load(p, __ATOMIC_RELAXED, __HIP_MEMORY_SCOPE_SYSTEM);
}
__device__ __forceinline__ void drain_stores(){
  __atomic_signal_fence(__ATOMIC_SEQ_CST);
  __builtin_amdgcn_s_waitcnt(0);
  __atomic_signal_fence(__ATOMIC_SEQ_CST);
}

// ---------- pack kernels ----------
__global__ void pack_bf16v(const float* __restrict__ in, unsigned short* __restrict__ out, int n4){
  int i = blockIdx.x * blockDim.x + threadIdx.x;
  int stride = gridDim.x * blockDim.x;
  for (; i < n4; i += stride){
    float4 v = ((const float4*)in)[i];
    ushort4 o;
    o.x = f2bf(v.x); o.y = f2bf(v.y); o.z = f2bf(v.z); o.w = f2bf(v.w);
    ((ushort4*)out)[i] = o;
  }
}

// KRP[q][k][jj]: per-WG-contiguous gate weights. jj in [0,256) maps to
// logical column J = (jj>>6)*256 + q*64 + (jj&63); rows 0..767 = K, 768..1023 = R.
// Total elements = 4*1024*256 = 1,048,576 -> grid MUST be 4096 x 256 (R4 bug: 8192
// overran the 2 MB buffer and trashed Wab/x1).
__global__ void pack_KRP(const float* __restrict__ K, const float* __restrict__ R,
                         unsigned short* __restrict__ KRP){
  int idx = blockIdx.x * 256 + threadIdx.x;    // 4096 blocks -> 1M exactly
  int q  = idx >> 18;
  int k  = (idx >> 8) & 1023;
  int jj = idx & 255;
  int J  = (jj >> 6)*256 + q*64 + (jj & 63);
  float v = (k < 768) ? K[(size_t)k*1024 + J] : R[(size_t)(k - 768)*1024 + J];
  KRP[idx] = f2bf(v);
}

// ---------- secrets = trans @ emb_W + emb_b : [32768,64]@[64,256] ----------
__global__ __launch_bounds__(256) void emb_gemm(const float* __restrict__ trans,
    const float* __restrict__ W, const float* __restrict__ bias, float* __restrict__ out){
  __shared__ __align__(16) float aT[64*20];
  const int row0 = blockIdx.x * 16;
  const int tid = threadIdx.x;
  {
    int r = tid >> 6, k = tid & 63;
    for (int rr = r; rr < 16; rr += 4)
      aT[k*20 + rr] = trans[(size_t)(row0 + rr)*64 + k];
  }
  __syncthreads();
  const int j = tid;
  float bj = bias[j];
  float acc[16];
  #pragma unroll
  for (int r = 0; r < 16; ++r) acc[r] = bj;
  for (int k = 0; k < 64; ++k){
    float w = W[(size_t)k*UU + j];
    const float4* a4 = (const float4*)(aT + k*20);
    float4 q0 = a4[0], q1 = a4[1], q2 = a4[2], q3 = a4[3];
    acc[0]+=q0.x*w;  acc[1]+=q0.y*w;  acc[2]+=q0.z*w;  acc[3]+=q0.w*w;
    acc[4]+=q1.x*w;  acc[5]+=q1.y*w;  acc[6]+=q1.z*w;  acc[7]+=q1.w*w;
    acc[8]+=q2.x*w;  acc[9]+=q2.y*w;  acc[10]+=q2.z*w; acc[11]+=q2.w*w;
    acc[12]+=q3.x*w; acc[13]+=q3.y*w; acc[14]+=q3.z*w; acc[15]+=q3.w*w;
  }
  #pragma unroll
  for (int r = 0; r < 16; ++r)
    out[(size_t)(row0 + r)*UU + j] = acc[r];
}

// ---------- enc = speech @ Ua + Ua_b, stored bf16 [B][TE][U] ----------
__global__ __launch_bounds__(256) void enc_gemm(const float* __restrict__ speech,
    const float* __restrict__ Ua, const float* __restrict__ Uab,
    unsigned short* __restrict__ enc){
  __shared__ __align__(16) float aT[512*20];
  const int wg = blockIdx.x;
  const int b = wg >> 6, tb = (wg & 63) * 16;
  const int tid = threadIdx.x;
  const float* sp = speech + ((size_t)b*TE + tb)*EE;
  for (int it = 0; it < 32; ++it){
    int idx = tid + 256*it;
    int te = idx >> 9, e = idx & 511;
    aT[e*20 + te] = sp[(size_t)te*EE + e];
  }
  __syncthreads();
  const int j = tid;
  float bj = Uab[j];
  float acc[16];
  #pragma unroll
  for (int r = 0; r < 16; ++r) acc[r] = bj;
  const float* up = Ua + j;
  for (int e = 0; e < 512; ++e){
    float w = up[(size_t)e*UU];
    const float4* a4 = (const float4*)(aT + e*20);
    float4 q0 = a4[0], q1 = a4[1], q2 = a4[2], q3 = a4[3];
    acc[0]+=q0.x*w;  acc[1]+=q0.y*w;  acc[2]+=q0.z*w;  acc[3]+=q0.w*w;
    acc[4]+=q1.x*w;  acc[5]+=q1.y*w;  acc[6]+=q1.z*w;  acc[7]+=q1.w*w;
    acc[8]+=q2.x*w;  acc[9]+=q2.y*w;  acc[10]+=q2.z*w; acc[11]+=q2.w*w;
    acc[12]+=q3.x*w; acc[13]+=q3.y*w; acc[14]+=q3.z*w; acc[15]+=q3.w*w;
  }
  unsigned short* op = enc + ((size_t)b*TE + tb)*UU + j;
  #pragma unroll
  for (int r = 0; r < 16; ++r) op[(size_t)r*UU] = f2bf(acc[r]);
}

// ---------- persistent attention-LSTM scan ----------
// grid 256 = 64 batches x 4 WGs; 1024 threads. enc slice persisted in dynamic
// LDS (132 KB, stride 264 ushorts). All big streams are uint4 rolled loops
// (no per-thread arrays -> no scratch spill). 4-WG barriers: relaxed
// system-scope counter (no cache flushes).
__global__ __launch_bounds__(1024) void scan_kernel(
    const float* __restrict__ x_seq, float* __restrict__ y_out,
    const unsigned short* __restrict__ enc, const unsigned short* __restrict__ speech,
    const unsigned short* __restrict__ KRP, const unsigned short* __restrict__ Wab,
    const float* __restrict__ Wa_b, const float* __restrict__ va,
    const float* __restrict__ gate_b,
    float* __restrict__ pctx_g, float* __restrict__ l_g, float* __restrict__ h_g,
    unsigned int* __restrict__ ctr){
  extern __shared__ __align__(16) unsigned short enc_l[];   // [256][264] = 132 KB
  __shared__ float2 sva[256];        // (s[u], va[u])
  __shared__ float cat[1024];        // [0,256)=x_t  [256,768)=ctx  [768,1024)=h_{t-1}
  __shared__ float c_lds[64];
  __shared__ float lds_logit[256];
  __shared__ float p_lds[256];
  __shared__ float lds_pctx[512];
  __shared__ float lds_z[256];
  __shared__ float s_acc[256];
  __shared__ float red[32];
  __shared__ float nmi[2];

  const int tid = threadIdx.x;
  const int wg = blockIdx.x;
  const int b = wg >> 2, q = wg & 3;
  const int lane = tid & 63, wave = tid >> 6;
  unsigned int bar = 0;
  unsigned int* cptr = &ctr[b*16];

  // one-time: stage this WG's enc slice (256 te x 256 u bf16) into LDS
  {
    const uint4* ep4 = (const uint4*)(enc + ((size_t)b*TE + q*256)*UU);
    #pragma unroll
    for (int i = 0; i < 8; ++i){
      int idx = tid + 1024*i;                   // 8192 uint4
      int te_l = idx >> 5, ch = idx & 31;
      uint4 v = ep4[(size_t)te_l*32 + ch];
      *(uint4*)(enc_l + (size_t)te_l*264 + ch*8) = v;
    }
  }
  if (tid < 256){ sva[tid] = make_float2(Wa_b[tid], va[tid]); cat[768 + tid] = 0.f; }
  if (tid < 64) c_lds[tid] = 0.f;
  __syncthreads();

  for (int t = 0; t < TD; ++t){
    if (tid < 256){ lds_logit[tid] = 0.f; lds_z[tid] = 0.f; s_acc[tid] = 0.f; }
    if (tid < 512) lds_pctx[tid] = 0.f;
    __syncthreads();

    // ---- P1: attention logits from LDS enc (|logit| <= ||va||_1, no max-sub) ----
    {
      const int g = wave & 3, r = wave >> 2;
      const int te_l = g*64 + lane;             // local te 0..255
      const unsigned short* ep = enc_l + (size_t)te_l*264 + r*64;
      float acc = 0.f;
      #pragma unroll
      for (int c = 0; c < 8; ++c){
        uint4 v = *(const uint4*)(ep + c*8);
        const int ub = r*64 + c*8;
        unsigned int wv[4] = {v.x, v.y, v.z, v.w};
        #pragma unroll
        for (int i = 0; i < 4; ++i){
          float2 s0 = sva[ub + 2*i];
          float2 s1 = sva[ub + 2*i + 1];
          acc += s0.y * tanh_fast(s0.x + bflo(wv[i]));
          acc += s1.y * tanh_fast(s1.x + bfhi(wv[i]));
        }
      }
      atomicAdd(&lds_logit[te_l], acc);
    }
    __syncthreads();

    // ---- P2: p = exp(logit), wave partial sums ----
    if (tid < 256){
      float p = fexp2(lds_logit[tid] * 1.442695041f);
      p_lds[tid] = p;
      float s = p;
      #pragma unroll
      for (int o = 32; o > 0; o >>= 1) s += __shfl_xor(s, o);
      if (lane == 0) red[wave] = s;
    }
    __syncthreads();

    // ---- P3: partial ctx = sum_te p[te]*speech[te][:]  (uint4 stream) ----
    {
      const int c = tid & 63, tg = tid >> 6;    // e-chunk (8 e), te-group (16 te)
      const uint4* sp4 = (const uint4*)speech + ((size_t)b*TE + q*256 + tg*16)*64 + c;
      float a0=0.f,a1=0.f,a2=0.f,a3=0.f,a4=0.f,a5=0.f,a6=0.f,a7=0.f;
      #pragma unroll 4
      for (int i = 0; i < 16; ++i){
        uint4 w = sp4[(size_t)i*64];
        float p = p_lds[tg*16 + i];
        a0 += p*bflo(w.x); a1 += p*bfhi(w.x);
        a2 += p*bflo(w.y); a3 += p*bfhi(w.y);
        a4 += p*bflo(w.z); a5 += p*bfhi(w.z);
        a6 += p*bflo(w.w); a7 += p*bfhi(w.w);
      }
      atomicAdd(&lds_pctx[c*8+0], a0); atomicAdd(&lds_pctx[c*8+1], a1);
      atomicAdd(&lds_pctx[c*8+2], a2); atomicAdd(&lds_pctx[c*8+3], a3);
      atomicAdd(&lds_pctx[c*8+4], a4); atomicAdd(&lds_pctx[c*8+5], a5);
      atomicAdd(&lds_pctx[c*8+6], a6); atomicAdd(&lds_pctx[c*8+7], a7);
    }
    __syncthreads();
    if (tid < 512) gstore(&pctx_g[((size_t)(b*4 + q))*512 + tid], lds_pctx[tid]);
    if (tid == 0)  gstore(&l_g[b*4 + q], red[0] + red[1] + red[2] + red[3]);
    drain_stores();
    __syncthreads();
    // ---- barrier A (partials visible at L3) ----
    bar += 4;
    if (tid == 0){
      __hip_atomic_fetch_add(cptr, 1u, __ATOMIC_RELAXED, __HIP_MEMORY_SCOPE_SYSTEM);
      while (__hip_atomic_load(cptr, __ATOMIC_RELAXED, __HIP_MEMORY_SCOPE_SYSTEM) < bar)
        __builtin_amdgcn_s_sleep(2);
    }
    __syncthreads();

    // ---- merge ctx; load x_t ----
    if (tid < 512){
      float l0 = gload(&l_g[b*4+0]), l1 = gload(&l_g[b*4+1]);
      float l2 = gload(&l_g[b*4+2]), l3 = gload(&l_g[b*4+3]);
      float linv = frcp_(l0 + l1 + l2 + l3);
      float s0 = gload(&pctx_g[((size_t)(b*4+0))*512 + tid])
               + gload(&pctx_g[((size_t)(b*4+1))*512 + tid])
               + gload(&pctx_g[((size_t)(b*4+2))*512 + tid])
               + gload(&pctx_g[((size_t)(b*4+3))*512 + tid]);
      cat[256 + tid] = s0 * linv;
    } else if (tid < 768){
      const int u = tid - 512;
      cat[u] = x_seq[((size_t)b*TD + t)*UU + u];
    }
    __syncthreads();

    // ---- gate GEMV: z[jj] for this WG's 256 columns (uint4 stream over KRP) ----
    {
      const int c = tid & 31, kg = tid >> 5;    // jj-chunk (8 j), k-group (32 k)
      const uint4* kp = (const uint4*)KRP + ((size_t)q*1024 + kg*32)*32 + c;
      float a0=0.f,a1=0.f,a2=0.f,a3=0.f,a4=0.f,a5=0.f,a6=0.f,a7=0.f;
      #pragma unroll 4
      for (int i = 0; i < 32; ++i){
        uint4 w = kp[(size_t)i*32];
        float ck = cat[kg*32 + i];
        a0 += ck*bflo(w.x); a1 += ck*bfhi(w.x);
        a2 += ck*bflo(w.y); a3 += ck*bfhi(w.y);
        a4 += ck*bflo(w.z); a5 += ck*bfhi(w.z);
        a6 += ck*bflo(w.w); a7 += ck*bfhi(w.w);
      }
      // lanes L and L+32 share c (kg pair) -> in-wave reduce, then one atomic set
      a0 += __shfl_xor(a0, 32); a1 += __shfl_xor(a1, 32);
      a2 += __shfl_xor(a2, 32); a3 += __shfl_xor(a3, 32);
      a4 += __shfl_xor(a4, 32); a5 += __shfl_xor(a5, 32);
      a6 += __shfl_xor(a6, 32); a7 += __shfl_xor(a7, 32);
      if (lane < 32){
        atomicAdd(&lds_z[c*8+0], a0); atomicAdd(&lds_z[c*8+1], a1);
        atomicAdd(&lds_z[c*8+2], a2); atomicAdd(&lds_z[c*8+3], a3);
        atomicAdd(&lds_z[c*8+4], a4); atomicAdd(&lds_z[c*8+5], a5);
        atomicAdd(&lds_z[c*8+6], a6); atomicAdd(&lds_z[c*8+7], a7);
      }
    }
    __syncthreads();

    // ---- LSTM pointwise (keras i,f,g,o), export h slice ----
    if (tid < 64){
      const int jj = q*64 + tid;
      float zi = lds_z[tid]       + gate_b[jj];
      float zf = lds_z[64 + tid]  + gate_b[256 + jj];
      float zg = lds_z[128 + tid] + gate_b[512 + jj];
      float zo = lds_z[192 + tid] + gate_b[768 + jj];
      float cn = sigmoid_fast(zf) * c_lds[tid] + sigmoid_fast(zi) * tanh_fast(zg);
      c_lds[tid] = cn;
      gstore(&h_g[(size_t)b*UU + jj], sigmoid_fast(zo) * tanh_fast(cn));
    }
    drain_stores();
    __syncthreads();
    // ---- barrier B (h slices visible) ----
    bar += 4;
    if (tid == 0){
      __hip_atomic_fetch_add(cptr, 1u, __ATOMIC_RELAXED, __HIP_MEMORY_SCOPE_SYSTEM);
      while (__hip_atomic_load(cptr, __ATOMIC_RELAXED, __HIP_MEMORY_SCOPE_SYSTEM) < bar)
        __builtin_amdgcn_s_sleep(2);
    }
    __syncthreads();

    if (tid < 256) cat[768 + tid] = gload(&h_g[(size_t)b*UU + tid]);
    __syncthreads();

    // ---- y_t = whatever_norm(h_t), once per batch (WG-uniform branch) ----
    if (q == 0){
      if (tid < 256){
        float hv = cat[768 + tid];
        float s1 = hv, s2 = hv*hv;
        #pragma unroll
        for (int o = 32; o > 0; o >>= 1){ s1 += __shfl_xor(s1, o); s2 += __shfl_xor(s2, o); }
        if (lane == 0){ red[wave*2] = s1; red[wave*2 + 1] = s2; }
      }
      __syncthreads();
      if (tid == 0){
        float m  = (red[0] + red[2] + red[4] + red[6]) * (1.f/256.f);
        float ms = (red[1] + red[3] + red[5] + red[7]) * (1.f/256.f);
        nmi[0] = m;
        nmi[1] = rsqrtf(ms - m*m + 1e-4f);
      }
      __syncthreads();
      if (tid < 256)
        y_out[((size_t)b*TD + t)*UU + tid] = (cat[768 + tid] - nmi[0]) * nmi[1];
    }

    // ---- s_{t+1} = h_t @ Wa + Wa_b (redundant per WG; uint4 stream) ----
    if (t < TD - 1){
      {
        const int c = tid & 31, kg = tid >> 5;  // u-chunk (8 u), k-group (8 k)
        const uint4* wp = (const uint4*)Wab + (size_t)(kg*8)*32 + c;
        float a0=0.f,a1=0.f,a2=0.f,a3=0.f,a4=0.f,a5=0.f,a6=0.f,a7=0.f;
        #pragma unroll 4
        for (int i = 0; i < 8; ++i){
          uint4 w = wp[(size_t)i*32];
          float hk = cat[768 + kg*8 + i];
          a0 += hk*bflo(w.x); a1 += hk*bfhi(w.x);
          a2 += hk*bflo(w.y); a3 += hk*bfhi(w.y);
          a4 += hk*bflo(w.z); a5 += hk*bfhi(w.z);
          a6 += hk*bflo(w.w); a7 += hk*bfhi(w.w);
        }
        a0 += __shfl_xor(a0, 32); a1 += __shfl_xor(a1, 32);
        a2 += __shfl_xor(a2, 32); a3 += __shfl_xor(a3, 32);
        a4 += __shfl_xor(a4, 32); a5 += __shfl_xor(a5, 32);
        a6 += __shfl_xor(a6, 32); a7 += __shfl_xor(a7, 32);
        if (lane < 32){
          atomicAdd(&s_acc[c*8+0], a0); atomicAdd(&s_acc[c*8+1], a1);
          atomicAdd(&s_acc[c*8+2], a2); atomicAdd(&s_acc[c*8+3], a3);
          atomicAdd(&s_acc[c*8+4], a4); atomicAdd(&s_acc[c*8+5], a5);
          atomicAdd(&s_acc[c*8+6], a6); atomicAdd(&s_acc[c*8+7], a7);
        }
      }
      __syncthreads();
      if (tid < 256) sva[tid].x = Wa_b[tid] + s_acc[tid];
    }
    __syncthreads();
  }
}

// ---------- head: norm(norm(y2@m1+b)@m2+b)@dW+db -> softmax ----------
__global__ __launch_bounds__(256) void head_kernel(const float* __restrict__ y2,
    const float* __restrict__ m1W, const float* __restrict__ m1b,
    const float* __restrict__ m2W, const float* __restrict__ m2b,
    const float* __restrict__ dW, const float* __restrict__ db,
    float* __restrict__ out){
  __shared__ __align__(16) float aT[256*20];
  __shared__ float t_lds[16*256];
  __shared__ float zl[16*64];
  __shared__ float mi[32];
  const int row0 = blockIdx.x * 16;
  const int tid = threadIdx.x;
  for (int it = 0; it < 16; ++it){
    int idx = tid + 256*it;
    int r = idx >> 8, k = idx & 255;
    aT[k*20 + r] = y2[(size_t)(row0 + r)*UU + k];
  }
  __syncthreads();

  #pragma unroll 1
  for (int pass = 0; pass < 2; ++pass){
    const float* Wp = pass ? m2W : m1W;
    const float* bp = pass ? m2b : m1b;
    const int j = tid;
    float bj = bp[j];
    float acc[16];
    #pragma unroll
    for (int r = 0; r < 16; ++r) acc[r] = bj;
    for (int k = 0; k < 256; ++k){
      float w = Wp[(size_t)k*UU + j];
      const float4* a4 = (const float4*)(aT + k*20);
      float4 q0 = a4[0], q1 = a4[1], q2 = a4[2], q3 = a4[3];
      acc[0]+=q0.x*w;  acc[1]+=q0.y*w;  acc[2]+=q0.z*w;  acc[3]+=q0.w*w;
      acc[4]+=q1.x*w;  acc[5]+=q1.y*w;  acc[6]+=q1.z*w;  acc[7]+=q1.w*w;
      acc[8]+=q2.x*w;  acc[9]+=q2.y*w;  acc[10]+=q2.z*w; acc[11]+=q2.w*w;
      acc[12]+=q3.x*w; acc[13]+=q3.y*w; acc[14]+=q3.z*w; acc[15]+=q3.w*w;
    }
    #pragma unroll
    for (int r = 0; r < 16; ++r) t_lds[r*256 + j] = acc[r];
    __syncthreads();
    {
      int r = tid >> 4, sg = tid & 15;
      float s1 = 0.f, s2 = 0.f;
      for (int c = 0; c < 16; ++c){
        float v = t_lds[r*256 + sg*16 + c];
        s1 += v; s2 += v*v;
      }
      for (int o = 1; o < 16; o <<= 1){ s1 += __shfl_xor(s1, o); s2 += __shfl_xor(s2, o); }
      if (sg == 0){
        float m = s1 * (1.f/256.f);
        float vv = s2 * (1.f/256.f) - m*m;
        mi[r*2] = m; mi[r*2+1] = rsqrtf(vv + 1e-4f);
      }
    }
    __syncthreads();
    {
      const int j2 = tid;
      #pragma unroll
      for (int r = 0; r < 16; ++r)
        aT[j2*20 + r] = (t_lds[r*256 + j2] - mi[r*2]) * mi[r*2+1];
    }
    __syncthreads();
  }

  for (int i = tid; i < 1024; i += 256) zl[i] = 0.f;
  __syncthreads();
  {
    const int j = tid & 63, kq = tid >> 6;
    float acc[16];
    #pragma unroll
    for (int r = 0; r < 16; ++r) acc[r] = 0.f;
    for (int k = 0; k < 64; ++k){
      float w = dW[(size_t)(kq*64 + k)*64 + j];
      const float4* a4 = (const float4*)(aT + (kq*64 + k)*20);
      float4 q0 = a4[0], q1 = a4[1], q2 = a4[2], q3 = a4[3];
      acc[0]+=q0.x*w;  acc[1]+=q0.y*w;  acc[2]+=q0.z*w;  acc[3]+=q0.w*w;
      acc[4]+=q1.x*w;  acc[5]+=q1.y*w;  acc[6]+=q1.z*w;  acc[7]+=q1.w*w;
      acc[8]+=q2.x*w;  acc[9]+=q2.y*w;  acc[10]+=q2.z*w; acc[11]+=q2.w*w;
      acc[12]+=q3.x*w; acc[13]+=q3.y*w; acc[14]+=q3.z*w; acc[15]+=q3.w*w;
    }
    #pragma unroll
    for (int r = 0; r < 16; ++r) atomicAdd(&zl[r*64 + j], acc[r]);
  }
  __syncthreads();
  if (tid < 16){
    const int r = tid;
    float mx = -1e30f;
    for (int j = 0; j < 64; ++j){ float v = zl[r*64 + j] + db[j]; zl[r*64 + j] = v; mx = fmaxf(mx, v); }
    float s = 0.f;
    for (int j = 0; j < 64; ++j){ float e = fexp2((zl[r*64 + j] - mx) * 1.442695041f); zl[r*64 + j] = e; s += e; }
    mi[r] = frcp_(s);
  }
  __syncthreads();
  for (int it = 0; it < 4; ++it){
    int idx = tid + 256*it;
    int r = idx >> 6, j = idx & 63;
    out[(size_t)(row0 + r)*64 + j] = zl[r*64 + j] * mi[r];
  }
}

// ---------- workspace layout (bytes) ----------
#define OFF_SPEECH 0u
#define OFF_ENC    67108864u
#define OFF_KR     100663296u
#define OFF_WA     102760448u
#define OFF_X1     102891520u
#define OFF_Y1     136445952u
#define OFF_PCTX   170000384u
#define OFF_L      170524672u
#define OFF_H      170528768u
#define OFF_CTR    170594304u

#define DYN_LDS    135168    // 256 rows x 264 ushorts

extern "C" void kernel_launch(void* const* d_in, const int* in_sizes, int n_in,
                              void* d_out, int out_size, void* d_ws, size_t ws_size,
                              hipStream_t stream){
  const float* trans  = (const float*)d_in[0];
  const float* speech = (const float*)d_in[1];
  const float* emb_W  = (const float*)d_in[2];
  const float* emb_b  = (const float*)d_in[3];
  const float* Ua_W[2]  = {(const float*)d_in[4],  (const float*)d_in[13]};
  const float* Ua_b[2]  = {(const float*)d_in[5],  (const float*)d_in[14]};
  const float* Wa_W[2]  = {(const float*)d_in[6],  (const float*)d_in[15]};
  const float* Wa_bv[2] = {(const float*)d_in[7],  (const float*)d_in[16]};
  const float* va_W[2]  = {(const float*)d_in[8],  (const float*)d_in[17]};
  // d_in[9]/d_in[18] = va_b: constant logit shift, softmax-invariant, dropped exactly.
  const float* Kw[2]    = {(const float*)d_in[10], (const float*)d_in[19]};
  const float* Rw[2]    = {(const float*)d_in[11], (const float*)d_in[20]};
  const float* bw[2]    = {(const float*)d_in[12], (const float*)d_in[21]};
  const float* m1W = (const float*)d_in[22];
  const float* m1b = (const float*)d_in[23];
  const float* m2W = (const float*)d_in[24];
  const float* m2b = (const float*)d_in[25];
  const float* dW  = (const float*)d_in[26];
  const float* db  = (const float*)d_in[27];

  char* ws = (char*)d_ws;
  unsigned short* speech_bf = (unsigned short*)(ws + OFF_SPEECH);
  unsigned short* enc  = (unsigned short*)(ws + OFF_ENC);
  unsigned short* KRP  = (unsigned short*)(ws + OFF_KR);
  unsigned short* Wab  = (unsigned short*)(ws + OFF_WA);
  float* x1   = (float*)(ws + OFF_X1);
  float* y1   = (float*)(ws + OFF_Y1);
  float* pctx = (float*)(ws + OFF_PCTX);
  float* lg   = (float*)(ws + OFF_L);
  float* hg   = (float*)(ws + OFF_H);
  unsigned int* ctr = (unsigned int*)(ws + OFF_CTR);
  float* y2 = x1;   // x1 dead after scan1 consumes it

  hipFuncSetAttribute((const void*)scan_kernel,
                      hipFuncAttributeMaxDynamicSharedMemorySize, DYN_LDS);

  hipMemsetAsync(ctr, 0, 4096, stream);
  pack_bf16v<<<4096, 256, 0, stream>>>(speech, speech_bf, B*TE*EE/4);
  emb_gemm<<<2048, 256, 0, stream>>>(trans, emb_W, emb_b, x1);

  for (int L = 0; L < 2; ++L){
    enc_gemm<<<4096, 256, 0, stream>>>(speech, Ua_W[L], Ua_b[L], enc);
    pack_KRP<<<4096, 256, 0, stream>>>(Kw[L], Rw[L], KRP);
    pack_bf16v<<<64, 256, 0, stream>>>(Wa_W[L], Wab, UU*UU/4);
    if (L == 1) hipMemsetAsync(ctr, 0, 4096, stream);
    scan_kernel<<<256, 1024, DYN_LDS, stream>>>(L == 0 ? x1 : y1, L == 0 ? y1 : y2,
        enc, speech_bf, KRP, Wab, Wa_bv[L], va_W[L], bw[L], pctx, lg, hg, ctr);
  }

  head_kernel<<<2048, 256, 0, stream>>>(y2, m1W, m1b, m2W, m2b, dW, db, (float*)d_out);
  (void)in_sizes; (void)n_in; (void)out_size; (void)ws_size;
}